// Round 19
// baseline (186.101 us; speedup 1.0000x reference)
//
#include <hip/hip_runtime.h>

// GCN: 3 layers GraphConv (norm='both'), N=50000, E=800000, D=128.
// Round 19: REVERT to round-17 (cooperative-launch experiment failed under
// graph capture: kernels never executed). 8-launch pipeline, known-good.
// Gathers: 16B/lane (4 edge-groups x 16 col-lanes, int4 = 8 bf16/lane).
//   out = M·(M^2 h · W123) + v2 c1^T + v1 c2^T + 1 b3^T,  v1=M·1, v2=M·v1.

#define NN 50000
#define NE 800000
#define DM 128
#define NB 196     // ceil(NN/256) scan blocks
#define NGB 12500  // gather blocks (NN*64/256)
#define CHN 12500  // nodes per histogram chunk (50KB LDS)
#define NCOP 32    // edge-slice copies per (array, chunk)
#define NFB 782    // bf16-conversion rider blocks

typedef unsigned short u16;
typedef __attribute__((ext_vector_type(8))) short bf16x8;
typedef __attribute__((ext_vector_type(4))) float f32x4;

__device__ __forceinline__ float bf2f(u16 u) {
  return __uint_as_float((unsigned)u << 16);
}
__device__ __forceinline__ u16 f2bf(float f) {
  unsigned x = __float_as_uint(f);
  return (u16)((x + 0x7fffu + ((x >> 16) & 1u)) >> 16);  // RNE, finite inputs
}
__device__ __forceinline__ float bflo(int u) { return __int_as_float(u << 16); }
__device__ __forceinline__ float bfhi(int u) { return __int_as_float(u & 0xffff0000); }

// grid 256: b = arr*128 + chunk*32 + copy. LDS histogram of its node chunk
// over its edge slice; non-atomic flush to hcop[b*CHN ..].
__global__ void k_hist(const int* __restrict__ src, const int* __restrict__ dst,
                       int* __restrict__ hcop) {
  __shared__ int h[CHN];
  int b = blockIdx.x;
  int arr   = b >> 7;
  int chunk = (b >> 5) & 3;
  int copy  = b & 31;
  const int* idx = arr ? dst : src;
  int lo = chunk * CHN;
  for (int i = threadIdx.x; i < CHN; i += 256) h[i] = 0;
  __syncthreads();
  const int4* e4 = reinterpret_cast<const int4*>(idx) + copy * (NE / 4 / NCOP);
  for (int i = threadIdx.x; i < NE / 4 / NCOP; i += 256) {
    int4 v = e4[i];
    unsigned a;
    a = (unsigned)(v.x - lo); if (a < (unsigned)CHN) atomicAdd(&h[a], 1);
    a = (unsigned)(v.y - lo); if (a < (unsigned)CHN) atomicAdd(&h[a], 1);
    a = (unsigned)(v.z - lo); if (a < (unsigned)CHN) atomicAdd(&h[a], 1);
    a = (unsigned)(v.w - lo); if (a < (unsigned)CHN) atomicAdd(&h[a], 1);
  }
  __syncthreads();
  int* o = hcop + (size_t)b * CHN;
  for (int i = threadIdx.x; i < CHN; i += 256) o[i] = h[i];
}

// ---- scan stage 1 (+bf16 conversion rider on blocks >= NB) ----
__global__ void k_scan_part(const int* __restrict__ hcop, int* __restrict__ co,
                            int* __restrict__ ci, int* __restrict__ bsum,
                            const float* __restrict__ feat, u16* __restrict__ featb) {
  __shared__ int s[256];
  int b = blockIdx.x;
  if (b >= NB) {
    size_t base = ((size_t)(b - NB) * 256 + threadIdx.x) * 8;
    const size_t stride = (size_t)NFB * 256 * 8;
#pragma unroll
    for (int it = 0; it < 4; ++it, base += stride) {
      if (base < (size_t)NN * DM) {
        float4 f0 = *reinterpret_cast<const float4*>(feat + base);
        float4 f1 = *reinterpret_cast<const float4*>(feat + base + 4);
        ushort4 u0 = make_ushort4(f2bf(f0.x), f2bf(f0.y), f2bf(f0.z), f2bf(f0.w));
        ushort4 u1 = make_ushort4(f2bf(f1.x), f2bf(f1.y), f2bf(f1.z), f2bf(f1.w));
        *reinterpret_cast<ushort4*>(featb + base) = u0;
        *reinterpret_cast<ushort4*>(featb + base + 4) = u1;
      }
    }
    return;
  }
  int i = b * 256 + threadIdx.x;
  int sco = 0, sci = 0;
  if (i < NN) {
    int ch = i / CHN;
    int loc = i - ch * CHN;
    const int* pco = hcop + (size_t)(ch * 32) * CHN + loc;
    const int* pci = hcop + (size_t)(128 + ch * 32) * CHN + loc;
#pragma unroll
    for (int p = 0; p < NCOP; ++p) {
      sco += pco[(size_t)p * CHN];
      sci += pci[(size_t)p * CHN];
    }
    co[i] = sco;
    ci[i] = sci;
  }
  s[threadIdx.x] = sci;
  __syncthreads();
  for (int off = 128; off > 0; off >>= 1) {
    if (threadIdx.x < off) s[threadIdx.x] += s[threadIdx.x + off];
    __syncthreads();
  }
  if (threadIdx.x == 0) bsum[b] = s[0];
}

// ---- merged: scan bsum in-block, per-node scan -> rowptr/norms, pcur fill ----
__global__ void k_scan_out2(const int* __restrict__ ci, const int* __restrict__ co,
                            const int* __restrict__ bsum, int* __restrict__ rowptr,
                            float* __restrict__ onorm, float* __restrict__ inorm,
                            const int* __restrict__ hcop_dst, int* __restrict__ pcur) {
  __shared__ int s[256];
  int t = threadIdx.x;
  int bv = (t < NB) ? bsum[t] : 0;
  s[t] = bv;
  __syncthreads();
  for (int off = 1; off < 256; off <<= 1) {
    int u = (t >= off) ? s[t - off] : 0;
    __syncthreads();
    s[t] += u;
    __syncthreads();
  }
  int boff_blk = s[blockIdx.x] - bsum[blockIdx.x];
  __syncthreads();

  int i = blockIdx.x * 256 + t;
  int v = (i < NN) ? ci[i] : 0;
  s[t] = v;
  __syncthreads();
  for (int off = 1; off < 256; off <<= 1) {
    int u = (t >= off) ? s[t - off] : 0;
    __syncthreads();
    s[t] += u;
    __syncthreads();
  }
  if (i < NN) {
    int ex = boff_blk + s[t] - v;
    rowptr[i] = ex;
    onorm[i] = rsqrtf(fmaxf((float)co[i], 1.0f));
    inorm[i] = rsqrtf(fmaxf((float)v, 1.0f));
    int ch = i / CHN;
    int loc = i - ch * CHN;
    const int* hb = hcop_dst + (size_t)(ch * 32) * CHN + loc;
    int* pb = pcur + (size_t)(ch * 32) * CHN + loc;
    int run = ex;
#pragma unroll
    for (int p = 0; p < NCOP; ++p) {
      pb[(size_t)p * CHN] = run;
      run += hb[(size_t)p * CHN];
    }
  }
  if (blockIdx.x == 0 && t == 0) rowptr[NN] = NE;
}

// (chunk,slice) CSR fill via LDS cursors, no global atomics.
__global__ void k_fill2(const int* __restrict__ src, const int* __restrict__ dst,
                        const int* __restrict__ pcur, int* __restrict__ col) {
  __shared__ int cur[CHN];
  int b = blockIdx.x;
  int copy  = b & 31;
  int lo = (b >> 5) * CHN;
  const int* pc = pcur + (size_t)b * CHN;
  for (int i = threadIdx.x; i < CHN; i += 256) cur[i] = pc[i];
  __syncthreads();
  const int4* s4 = reinterpret_cast<const int4*>(src) + copy * (NE / 4 / NCOP);
  const int4* d4 = reinterpret_cast<const int4*>(dst) + copy * (NE / 4 / NCOP);
  for (int i = threadIdx.x; i < NE / 4 / NCOP; i += 256) {
    int4 s = s4[i];
    int4 d = d4[i];
    unsigned a;
    int p;
    a = (unsigned)(d.x - lo); if (a < (unsigned)CHN) { p = atomicAdd(&cur[a], 1); col[p] = s.x; }
    a = (unsigned)(d.y - lo); if (a < (unsigned)CHN) { p = atomicAdd(&cur[a], 1); col[p] = s.y; }
    a = (unsigned)(d.z - lo); if (a < (unsigned)CHN) { p = atomicAdd(&cur[a], 1); col[p] = s.z; }
    a = (unsigned)(d.w - lo); if (a < (unsigned)CHN) { p = atomicAdd(&cur[a], 1); col[p] = s.w; }
  }
}

#define ACC8(uu, nn)                     \
  aa.x += (nn) * bflo((uu).x); ab.x += (nn) * bfhi((uu).x); \
  aa.y += (nn) * bflo((uu).y); ab.y += (nn) * bfhi((uu).y); \
  aa.z += (nn) * bflo((uu).z); ab.z += (nn) * bfhi((uu).z); \
  aa.w += (nn) * bflo((uu).w); ab.w += (nn) * bfhi((uu).w);

// ---- feature gather: Y = M X with bf16 X, 16B/lane loads.
// Wave = 4 edge-groups x 16 col-lanes; lane loads int4 (8 bf16) of one row.
// VMODE 0: none. 1: vout = M·1. 2: vout = M·vin.
// EXTRA==1: riders compute mCf = mA@mB (f32). EXTRA==2: mCt = bf16-T(mA@mB),
// +1 block for vc1/vc2. OUTMODE 0: bf16 aggb. 1: f32 outf + fused rank-1.
template <int VMODE, int EXTRA, int OUTMODE>
__global__ void k_gather_t(const u16* __restrict__ h, const int* __restrict__ rowptr,
                           const int* __restrict__ col, const float* __restrict__ onorm,
                           const float* __restrict__ inorm, const float* __restrict__ vin,
                           u16* __restrict__ aggb, float* __restrict__ outf,
                           float* __restrict__ vout,
                           const float* __restrict__ mA, const float* __restrict__ mB,
                           float* __restrict__ mCf, u16* __restrict__ mCt,
                           const float* __restrict__ vb1, const float* __restrict__ vB1,
                           float* __restrict__ vc1,
                           const float* __restrict__ vb2, const float* __restrict__ vB2,
                           float* __restrict__ vc2,
                           const float* __restrict__ pv1, const float* __restrict__ pv2,
                           const float* __restrict__ pc1, const float* __restrict__ pc2,
                           const float* __restrict__ pb3) {
  if (EXTRA) {
    int eb = (int)blockIdx.x - NGB;
    if (eb >= 0) {
      if (eb < 64) {            // mA @ mB, rows 2eb, 2eb+1
        int i0 = eb * 2 + (threadIdx.x >> 7);
        int j = threadIdx.x & 127;
        float acc = 0.f;
        for (int k = 0; k < DM; ++k) acc += mA[i0 * DM + k] * mB[k * DM + j];
        if (EXTRA == 1) mCf[i0 * DM + j] = acc;
        else            mCt[j * DM + i0] = f2bf(acc);  // bf16, transposed [n][k]
      } else if (EXTRA == 2) {
        int t = threadIdx.x;
        if (t < DM) {
          float acc = 0.f;
          for (int k = 0; k < DM; ++k) acc += vb1[k] * vB1[k * DM + t];
          vc1[t] = acc;
        } else {
          int j = t - DM;
          float acc = 0.f;
          for (int k = 0; k < DM; ++k) acc += vb2[k] * vB2[k * DM + j];
          vc2[j] = acc;
        }
      }
      return;
    }
  }
  int tid = blockIdx.x * blockDim.x + threadIdx.x;
  int n = tid >> 6;
  if (n >= NN) return;
  int g   = (threadIdx.x >> 4) & 3;   // edge group within wave
  int l16 = threadIdx.x & 15;         // 16B column slot (8 bf16)
  int beg = rowptr[n], end = rowptr[n + 1];
  const int4* h16 = reinterpret_cast<const int4*>(h);  // row = 16 int4
  float4 aa = make_float4(0.f, 0.f, 0.f, 0.f);  // even cols
  float4 ab = make_float4(0.f, 0.f, 0.f, 0.f);  // odd cols
  float av = 0.f;
  int e = beg + g;
  for (; e + 4 < end; e += 8) {
    int s0 = col[e], s1 = col[e + 4];
    float n0 = onorm[s0], n1 = onorm[s1];
    int4 u0 = h16[(size_t)s0 * 16 + l16];
    int4 u1 = h16[(size_t)s1 * 16 + l16];
    if (VMODE == 1) av += n0 + n1;
    if (VMODE == 2) av += n0 * vin[s0] + n1 * vin[s1];
    ACC8(u0, n0)
    ACC8(u1, n1)
  }
  for (; e < end; e += 4) {
    int s0 = col[e];
    float n0 = onorm[s0];
    int4 u0 = h16[(size_t)s0 * 16 + l16];
    if (VMODE == 1) av += n0;
    if (VMODE == 2) av += n0 * vin[s0];
    ACC8(u0, n0)
  }
  // reduce across the 4 edge-groups
  aa.x += __shfl_xor(aa.x, 16); aa.y += __shfl_xor(aa.y, 16);
  aa.z += __shfl_xor(aa.z, 16); aa.w += __shfl_xor(aa.w, 16);
  ab.x += __shfl_xor(ab.x, 16); ab.y += __shfl_xor(ab.y, 16);
  ab.z += __shfl_xor(ab.z, 16); ab.w += __shfl_xor(ab.w, 16);
  aa.x += __shfl_xor(aa.x, 32); aa.y += __shfl_xor(aa.y, 32);
  aa.z += __shfl_xor(aa.z, 32); aa.w += __shfl_xor(aa.w, 32);
  ab.x += __shfl_xor(ab.x, 32); ab.y += __shfl_xor(ab.y, 32);
  ab.z += __shfl_xor(ab.z, 32); ab.w += __shfl_xor(ab.w, 32);
  if (VMODE) { av += __shfl_xor(av, 16); av += __shfl_xor(av, 32); }
  if (g == 0) {
    float sc = inorm[n];
    aa.x *= sc; aa.y *= sc; aa.z *= sc; aa.w *= sc;
    ab.x *= sc; ab.y *= sc; ab.z *= sc; ab.w *= sc;
    if (OUTMODE == 0) {
      int4 o;
      o.x = ((int)f2bf(ab.x) << 16) | f2bf(aa.x);
      o.y = ((int)f2bf(ab.y) << 16) | f2bf(aa.y);
      o.z = ((int)f2bf(ab.z) << 16) | f2bf(aa.z);
      o.w = ((int)f2bf(ab.w) << 16) | f2bf(aa.w);
      reinterpret_cast<int4*>(aggb)[(size_t)n * 16 + l16] = o;
    } else {
      int jc = l16 * 8;
      float4 e1a = *reinterpret_cast<const float4*>(pc1 + jc);
      float4 e1b = *reinterpret_cast<const float4*>(pc1 + jc + 4);
      float4 e2a = *reinterpret_cast<const float4*>(pc2 + jc);
      float4 e2b = *reinterpret_cast<const float4*>(pc2 + jc + 4);
      float4 e3a = *reinterpret_cast<const float4*>(pb3 + jc);
      float4 e3b = *reinterpret_cast<const float4*>(pb3 + jc + 4);
      float q1 = pv1[n], q2 = pv2[n];
      float4 o0, o1;
      o0.x = aa.x + q2 * e1a.x + q1 * e2a.x + e3a.x;
      o0.y = ab.x + q2 * e1a.y + q1 * e2a.y + e3a.y;
      o0.z = aa.y + q2 * e1a.z + q1 * e2a.z + e3a.z;
      o0.w = ab.y + q2 * e1a.w + q1 * e2a.w + e3a.w;
      o1.x = aa.z + q2 * e1b.x + q1 * e2b.x + e3b.x;
      o1.y = ab.z + q2 * e1b.y + q1 * e2b.y + e3b.y;
      o1.z = aa.w + q2 * e1b.z + q1 * e2b.z + e3b.z;
      o1.w = ab.w + q2 * e1b.w + q1 * e2b.w + e3b.w;
      *reinterpret_cast<float4*>(outf + (size_t)n * DM + jc) = o0;
      *reinterpret_cast<float4*>(outf + (size_t)n * DM + jc + 4) = o1;
    }
    if (VMODE && l16 == 0) vout[n] = av * sc;
  }
}

// ---- MFMA GEMM: T[50000x128] = A @ W123, bf16 in/out (Bt = W123^T bf16).
__launch_bounds__(256, 4)
__global__ void k_gemm_mfma(const u16* __restrict__ A, const u16* __restrict__ Bt,
                            u16* __restrict__ T) {
  int w = threadIdx.x >> 6;
  int l = threadIdx.x & 63;
  int rbase = blockIdx.x * 32 + 16 * (w & 1);
  int jb0   = 64 * (w >> 1);
  int row = rbase + (l & 15);
  int rr = row < NN ? row : NN - 1;
  int kg = (l >> 4) * 8;
  const short* As = reinterpret_cast<const short*>(A);
  const short* Bs = reinterpret_cast<const short*>(Bt);
  bf16x8 fa0 = *reinterpret_cast<const bf16x8*>(As + (size_t)rr * DM + 0 * 32 + kg);
  bf16x8 fa1 = *reinterpret_cast<const bf16x8*>(As + (size_t)rr * DM + 1 * 32 + kg);
  bf16x8 fa2 = *reinterpret_cast<const bf16x8*>(As + (size_t)rr * DM + 2 * 32 + kg);
  bf16x8 fa3 = *reinterpret_cast<const bf16x8*>(As + (size_t)rr * DM + 3 * 32 + kg);
#pragma unroll
  for (int ct = 0; ct < 4; ++ct) {
    int jb = jb0 + ct * 16;
    const short* bp = Bs + (size_t)(jb + (l & 15)) * DM + kg;
    bf16x8 fb0 = *reinterpret_cast<const bf16x8*>(bp + 0 * 32);
    bf16x8 fb1 = *reinterpret_cast<const bf16x8*>(bp + 1 * 32);
    bf16x8 fb2 = *reinterpret_cast<const bf16x8*>(bp + 2 * 32);
    bf16x8 fb3 = *reinterpret_cast<const bf16x8*>(bp + 3 * 32);
    f32x4 c = {0.f, 0.f, 0.f, 0.f};
    c = __builtin_amdgcn_mfma_f32_16x16x32_bf16(fa0, fb0, c, 0, 0, 0);
    c = __builtin_amdgcn_mfma_f32_16x16x32_bf16(fa1, fb1, c, 0, 0, 0);
    c = __builtin_amdgcn_mfma_f32_16x16x32_bf16(fa2, fb2, c, 0, 0, 0);
    c = __builtin_amdgcn_mfma_f32_16x16x32_bf16(fa3, fb3, c, 0, 0, 0);
    int orow = rbase + (l >> 4) * 4;
    int ocol = jb + (l & 15);
#pragma unroll
    for (int r = 0; r < 4; ++r) {
      if (orow + r < NN) T[(size_t)(orow + r) * DM + ocol] = f2bf(c[r]);
    }
  }
}

extern "C" void kernel_launch(void* const* d_in, const int* in_sizes, int n_in,
                              void* d_out, int out_size, void* d_ws, size_t ws_size,
                              hipStream_t stream) {
  const float* in_feat = (const float*)d_in[0];
  const int*   ei      = (const int*)d_in[1];
  const float* Ws      = (const float*)d_in[2];
  const float* bs      = (const float*)d_in[3];
  float* out = (float*)d_out;

  const int* src = ei;
  const int* dst = ei + NE;
  const float* W1 = Ws;
  const float* W2 = Ws + DM * DM;
  const float* W3 = Ws + 2 * DM * DM;
  const float* b1 = bs;
  const float* b2 = bs + DM;
  const float* b3 = bs + 2 * DM;

  // 16B-aligned-first workspace layout (bf16 matrices accessed as int4)
  char* w = (char*)d_ws;
  int* hcop   = (int*)w;            w += (size_t)256 * CHN * sizeof(int);   // 12.8MB
  u16* featb  = (u16*)w;            w += (size_t)NN * DM * sizeof(u16);     // bf16 in_feat
  u16* g1b    = (u16*)w;            w += (size_t)NN * DM * sizeof(u16);     // bf16 M h
  u16* g2b    = (u16*)w;            w += (size_t)NN * DM * sizeof(u16);     // bf16 M^2 h
  u16* tb     = (u16*)w;            w += (size_t)NN * DM * sizeof(u16);     // bf16 g2 W123
  u16* W123t  = (u16*)w;            w += DM * DM * sizeof(u16);             // bf16 [n][k]
  float* W23  = (float*)w;          w += DM * DM * sizeof(float);
  int* co     = (int*)w;            w += NN * sizeof(int);
  int* ci     = (int*)w;            w += NN * sizeof(int);
  int* rowptr = (int*)w;            w += (NN + 1) * sizeof(int);
  int* bsum   = (int*)w;            w += NB * sizeof(int);
  int* col    = (int*)w;            w += NE * sizeof(int);
  float* onorm = (float*)w;         w += NN * sizeof(float);
  float* inorm = (float*)w;         w += NN * sizeof(float);
  float* v1    = (float*)w;         w += NN * sizeof(float);
  float* v2    = (float*)w;         w += NN * sizeof(float);
  float* c1    = (float*)w;         w += DM * sizeof(float);
  float* c2    = (float*)w;         w += DM * sizeof(float);

  int* pcur = hcop;                                // aliases consumed src half
  const int* hcop_dst = hcop + (size_t)128 * CHN;

  // graph preprocessing (no global atomics anywhere)
  k_hist<<<256, 256, 0, stream>>>(src, dst, hcop);
  k_scan_part<<<NB + NFB, 256, 0, stream>>>(hcop, co, ci, bsum, in_feat, featb);
  k_scan_out2<<<NB, 256, 0, stream>>>(ci, co, bsum, rowptr, onorm, inorm, hcop_dst, pcur);
  k_fill2<<<128, 256, 0, stream>>>(src, dst, pcur, col);

  // g1 = M h (+v1, +W23 rider); g2 = M g1 (+v2, +W123t/c1/c2 riders)
  k_gather_t<1, 1, 0><<<NGB + 64, 256, 0, stream>>>(featb, rowptr, col, onorm, inorm,
                                                    nullptr, g1b, nullptr, v1,
                                                    W2, W3, W23, nullptr,
                                                    nullptr, nullptr, nullptr,
                                                    nullptr, nullptr, nullptr,
                                                    nullptr, nullptr, nullptr, nullptr, nullptr);
  k_gather_t<2, 2, 0><<<NGB + 65, 256, 0, stream>>>(g1b, rowptr, col, onorm, inorm,
                                                    v1, g2b, nullptr, v2,
                                                    W1, W23, nullptr, W123t,
                                                    b1, W23, c1, b2, W3, c2,
                                                    nullptr, nullptr, nullptr, nullptr, nullptr);
  // t = g2 @ W123 (bf16 MFMA)
  k_gemm_mfma<<<(NN + 31) / 32, 256, 0, stream>>>(g2b, W123t, tb);
  // out = M t + rank-1 terms (fused epilogue)
  k_gather_t<0, 0, 1><<<NGB, 256, 0, stream>>>(tb, rowptr, col, onorm, inorm,
                                               nullptr, nullptr, out, nullptr,
                                               nullptr, nullptr, nullptr, nullptr,
                                               nullptr, nullptr, nullptr,
                                               nullptr, nullptr, nullptr,
                                               v1, v2, c1, c2, b3);
}